// Round 1
// 81.376 us; speedup vs baseline: 3.7365x; 3.7365x over previous
//
#include <hip/hip_runtime.h>
#include <hip/hip_fp16.h>

// HMM forward-backward smoother, B=16, T=8192, C=170.
// T = off*11^T + (alpha-off)*I  =>  (u @ T)[j] = off*sum(u) + (alpha-off)*u[j]
// UNNORMALIZED scaled linear recursions (scale cancels in final softmax):
//   fwd:  v' = (off*S + dd*u) * l,  S = sum(u),  u = v*l_t   (rescale by 1/S every 4 steps)
//   bwd:  q' = off*S + dd*w,       S = sum(w),  w = l_{t+1}*q
// Wave-wide sum via DPP (v_add_f32_dpp row_shr/row_bcast + readlane 63):
// ~10x lower dependent latency than ds_swizzle-based __shfl_xor.
// Chunked over time LCH=32 with WARM=32 warmup (mixing ~0.58/step => err ~3e-8).
// 4096 single-wave WGs -> ~14 WG/CU (LDS-capped) for latency hiding.

#define NCLS 170
#define BB 16
#define TT 8192
#define LCH 32
#define WARM 32
#define NCHUNK (TT / LCH)   // 256
#define PPAD 176            // fp16 row stride in LDS (170 rounded up)

struct Row { float x, y, z; };

// 64-lane sum, result broadcast to all lanes via readlane.
// Canonical gfx9 DPP reduction: prefix within 16-lane rows, then bcast15/bcast31.
__device__ __forceinline__ float wave_sum_b(float x) {
  x += __int_as_float(__builtin_amdgcn_update_dpp(0, __float_as_int(x), 0x111, 0xF, 0xF, true)); // row_shr:1
  x += __int_as_float(__builtin_amdgcn_update_dpp(0, __float_as_int(x), 0x112, 0xF, 0xF, true)); // row_shr:2
  x += __int_as_float(__builtin_amdgcn_update_dpp(0, __float_as_int(x), 0x114, 0xF, 0xF, true)); // row_shr:4
  x += __int_as_float(__builtin_amdgcn_update_dpp(0, __float_as_int(x), 0x118, 0xF, 0xF, true)); // row_shr:8
  x += __int_as_float(__builtin_amdgcn_update_dpp(0, __float_as_int(x), 0x142, 0xA, 0xF, true)); // row_bcast:15
  x += __int_as_float(__builtin_amdgcn_update_dpp(0, __float_as_int(x), 0x143, 0xC, 0xF, true)); // row_bcast:31
  return __int_as_float(__builtin_amdgcn_readlane(__float_as_int(x), 63));
}

__global__ __launch_bounds__(64, 4) void hmm_fb(const float* __restrict__ logits,
                                                const float* __restrict__ trans,
                                                const float* __restrict__ initd,
                                                float* __restrict__ out) {
  __shared__ __half pbuf[LCH * PPAD];   // 11264 B
  const int lane = threadIdx.x;

  // XCD-aware swizzle: 4096 WGs, 8 XCDs -> contiguous 512-chunk ranges per XCD
  // so neighboring chunks share L2 for the warmup-overlap reads.
  const int d = blockIdx.x;
  const int o = (d & 7) * (BB * NCHUNK / 8) + (d >> 3);
  const int b = o / NCHUNK;
  const int chunk = o % NCHUNK;
  const int t0 = chunk * LCH;
  const int t1 = t0 + LCH;

  // reference uses log(T + 1e-12); reproduce exactly in linear domain
  const float off = trans[1] + 1e-12f;   // off-diagonal element
  const float dia = trans[0] + 1e-12f;   // diagonal element
  const float dd = dia - off;

  const int c0 = lane, c1 = lane + 64, c2 = lane + 128;
  const bool cok = (c2 < NCLS);
  const float* lg = logits + (size_t)b * TT * NCLS;

  auto ldraw = [&](int t) -> Row {
    const float* r = lg + (size_t)t * NCLS;
    Row w;
    w.x = r[c0];
    w.y = r[c1];
    w.z = cok ? r[c2] : 0.f;
    return w;
  };
  // exp applied per unroll-group, off the recursion chain; invalid lanes -> 0
  auto eRow = [&](Row w) -> Row {
    Row e;
    e.x = __expf(w.x);
    e.y = __expf(w.y);
    e.z = cok ? __expf(w.z) : 0.f;
    return e;
  };

  // ---------------- forward ----------------
  float v0, v1, v2s;   // unnormalized predictive message
  float lastS = 1.f;
  int ts;
  if (t0 == 0) {
    ts = 0;                                   // exact initial distribution
    v0 = initd[c0];
    v1 = initd[c1];
    v2s = cok ? initd[c2] : 0.f;
  } else {
    ts = t0 - WARM;                           // warmup from uniform
    v0 = 1.f; v1 = 1.f; v2s = cok ? 1.f : 0.f;
  }

  auto fstep = [&](Row e, int t) {
    float u0 = v0 * e.x, u1 = v1 * e.y, u2 = v2s * e.z;  // e.z==0 on invalid lanes
    float S = wave_sum_b(u0 + u1 + u2);
    lastS = S;
    if (t >= t0) {                            // store normalized filtered msg (fp16)
      float inv = __builtin_amdgcn_rcpf(S);   // off-chain; common scale cancels
      int tt = t - t0;
      pbuf[tt * PPAD + c0] = __float2half(u0 * inv);
      pbuf[tt * PPAD + c1] = __float2half(u1 * inv);
      if (cok) pbuf[tt * PPAD + c2] = __float2half(u2 * inv);
    }
    float os = off * S;                       // predict (unnormalized)
    v0 = __fmaf_rn(dd, u0, os);
    v1 = __fmaf_rn(dd, u1, os);
    v2s = __fmaf_rn(dd, u2, os);              // garbage on invalid lanes, killed by e.z=0
  };

  {
    Row r0 = ldraw(ts);
    Row r1 = ldraw(ts + 1);
    Row r2 = ldraw(ts + 2);
    Row r3 = ldraw(ts + 3);
    for (int t = ts; t < t1; t += 4) {
      int tn = t + 4;
      Row n0 = ldraw(tn + 0 < t1 ? tn + 0 : t1 - 1);
      Row n1 = ldraw(tn + 1 < t1 ? tn + 1 : t1 - 1);
      Row n2 = ldraw(tn + 2 < t1 ? tn + 2 : t1 - 1);
      Row n3 = ldraw(tn + 3 < t1 ? tn + 3 : t1 - 1);
      Row e0 = eRow(r0), e1 = eRow(r1), e2 = eRow(r2), e3 = eRow(r3);
      fstep(e0, t);
      fstep(e1, t + 1);
      fstep(e2, t + 2);
      fstep(e3, t + 3);
      float rs = __builtin_amdgcn_rcpf(lastS);  // periodic rescale (pure scale)
      v0 *= rs; v1 *= rs; v2s *= rs;
      r0 = n0; r1 = n1; r2 = n2; r3 = n3;
    }
  }

  __syncthreads();

  // ---------------- backward + fused posterior ----------------
  float q0 = 1.f, q1 = 1.f, q2 = cok ? 1.f : 0.f;  // exact for last chunk (beta_T=0)
  int te2 = t1 + WARM;
  if (te2 > TT) te2 = TT;

  auto ldrawB = [&](int tp1) -> Row {
    // step at time t uses logits[t+1]; t+1==TT => virtual row logit=0 (l=1)
    int rr = tp1 < TT ? tp1 : TT - 1;
    Row w = ldraw(rr);
    if (tp1 >= TT) { w.x = 0.f; w.y = 0.f; w.z = 0.f; }
    return w;
  };

  auto bstep = [&](Row e, int t, bool wr) {
    float w0 = e.x * q0, w1 = e.y * q1, w2 = e.z * q2;
    float S = wave_sum_b(w0 + w1 + w2);
    lastS = S;
    float os = off * S;
    q0 = __fmaf_rn(dd, w0, os);
    q1 = __fmaf_rn(dd, w1, os);
    q2 = __fmaf_rn(dd, w2, os);
    if (wr) {                                 // posterior_t = normalize(p-hat .* q)
      int tt = t - t0;
      float a0 = __half2float(pbuf[tt * PPAD + c0]) * q0;
      float a1 = __half2float(pbuf[tt * PPAD + c1]) * q1;
      float a2 = cok ? __half2float(pbuf[tt * PPAD + c2]) * q2 : 0.f;
      float z = wave_sum_b(a0 + a1 + a2);
      float iz = __builtin_amdgcn_rcpf(z);
      float* op = out + ((size_t)b * TT + t) * NCLS;
      op[c0] = a0 * iz;
      op[c1] = a1 * iz;
      if (cok) op[c2] = a2 * iz;
    }
  };

  {
    const int tstart = te2 - 1;  // count = te2 - t0 = 64 (interior) or 32, both %4==0
    Row r0 = ldrawB(tstart + 1);
    Row r1 = ldrawB(tstart);
    Row r2 = ldrawB(tstart - 1);
    Row r3 = ldrawB(tstart - 2);
    for (int t = tstart; t > t0 - 1; t -= 4) {
      int p0i = t - 3 > t0 + 1 ? t - 3 : t0 + 1;
      int p1i = t - 4 > t0 + 1 ? t - 4 : t0 + 1;
      int p2i = t - 5 > t0 + 1 ? t - 5 : t0 + 1;
      int p3i = t - 6 > t0 + 1 ? t - 6 : t0 + 1;
      Row n0 = ldrawB(p0i);
      Row n1 = ldrawB(p1i);
      Row n2 = ldrawB(p2i);
      Row n3 = ldrawB(p3i);
      Row e0 = eRow(r0), e1 = eRow(r1), e2 = eRow(r2), e3 = eRow(r3);
      bstep(e0, t, t < t1);
      bstep(e1, t - 1, t - 1 < t1);
      bstep(e2, t - 2, t - 2 < t1);
      bstep(e3, t - 3, t - 3 < t1);
      float rs = __builtin_amdgcn_rcpf(lastS);  // periodic rescale (pure scale)
      q0 *= rs; q1 *= rs; q2 *= rs;
      r0 = n0; r1 = n1; r2 = n2; r3 = n3;
    }
  }
}

extern "C" void kernel_launch(void* const* d_in, const int* in_sizes, int n_in,
                              void* d_out, int out_size, void* d_ws, size_t ws_size,
                              hipStream_t stream) {
  const float* logits = (const float*)d_in[0];
  const float* trans  = (const float*)d_in[1];
  const float* initd  = (const float*)d_in[2];
  float* out = (float*)d_out;
  dim3 grid(BB * NCHUNK);
  dim3 block(64);
  hipLaunchKernelGGL(hmm_fb, grid, block, 0, stream, logits, trans, initd, out);
}

// Round 2
// 64.590 us; speedup vs baseline: 4.7075x; 1.2599x over previous
//
#include <hip/hip_runtime.h>
#include <hip/hip_fp16.h>

// HMM forward-backward smoother, B=16, T=8192, C=170.
// T = off*11^T + (alpha-off)*I  =>  (u @ T)[j] = off*sum(u) + (alpha-off)*u[j]
// UNNORMALIZED scaled linear recursions (scale cancels in final softmax):
//   fwd:  v' = off*S + dd*u,  S = sum(u),  u = v*l_t   (rescale by 1/S every 4 steps)
//   bwd:  q' = off*S + dd*w,  S = sum(w),  w = l_{t+1}*q
// Wave-wide sum via DPP (v_add_f32_dpp row_shr/row_bcast + readlane 63).
// Chunked over time LCH=32, WARM=16 (mixing ~0.58/step => warm err ~1.7e-4 << 1.25e-2).
// p-hat kept in REGISTERS (48 VGPRs, fully-unrolled main loops, no LDS):
// removes the 14-WG/CU LDS cap that forced a half-empty second dispatch round.
// 4096 single-wave WGs = 16 WG/CU resident in ONE round at <=128 VGPR.

#define NCLS 170
#define BB 16
#define TT 8192
#define LCH 32
#define WARM 16
#define NCHUNK (TT / LCH)   // 256

struct Row { float x, y, z; };

// 64-lane sum, result broadcast to all lanes via readlane.
__device__ __forceinline__ float wave_sum_b(float x) {
  x += __int_as_float(__builtin_amdgcn_update_dpp(0, __float_as_int(x), 0x111, 0xF, 0xF, true)); // row_shr:1
  x += __int_as_float(__builtin_amdgcn_update_dpp(0, __float_as_int(x), 0x112, 0xF, 0xF, true)); // row_shr:2
  x += __int_as_float(__builtin_amdgcn_update_dpp(0, __float_as_int(x), 0x114, 0xF, 0xF, true)); // row_shr:4
  x += __int_as_float(__builtin_amdgcn_update_dpp(0, __float_as_int(x), 0x118, 0xF, 0xF, true)); // row_shr:8
  x += __int_as_float(__builtin_amdgcn_update_dpp(0, __float_as_int(x), 0x142, 0xA, 0xF, true)); // row_bcast:15
  x += __int_as_float(__builtin_amdgcn_update_dpp(0, __float_as_int(x), 0x143, 0xC, 0xF, true)); // row_bcast:31
  return __int_as_float(__builtin_amdgcn_readlane(__float_as_int(x), 63));
}

__global__ __launch_bounds__(64, 4) void hmm_fb(const float* __restrict__ logits,
                                                const float* __restrict__ trans,
                                                const float* __restrict__ initd,
                                                float* __restrict__ out) {
  const int lane = threadIdx.x;

  // XCD-aware swizzle: 4096 WGs, 8 XCDs -> contiguous ranges per XCD.
  const int d = blockIdx.x;
  const int o = (d & 7) * (BB * NCHUNK / 8) + (d >> 3);
  const int b = o / NCHUNK;
  const int chunk = o % NCHUNK;
  const int t0 = chunk * LCH;
  const int t1 = t0 + LCH;

  // reference uses log(T + 1e-12); reproduce exactly in linear domain
  const float off = trans[1] + 1e-12f;   // off-diagonal element
  const float dia = trans[0] + 1e-12f;   // diagonal element
  const float dd = dia - off;

  const int c0 = lane, c1 = lane + 64, c2 = lane + 128;
  const bool cok = (c2 < NCLS);
  const float* lg = logits + (size_t)b * TT * NCLS;

  auto ldraw = [&](int t) -> Row {
    const float* r = lg + (size_t)t * NCLS;
    Row w;
    w.x = r[c0];
    w.y = r[c1];
    w.z = cok ? r[c2] : 0.f;
    return w;
  };
  auto eRow = [&](const Row& w) -> Row {
    Row e;
    e.x = __expf(w.x);
    e.y = __expf(w.y);
    e.z = cok ? __expf(w.z) : 0.f;
    return e;
  };

  // p-hat register store: 32 steps x 3 fp16 per lane (all indices compile-time)
  __half2 ph01[LCH];       // {p0,p1} per step
  __half2 ph2[LCH / 2];    // p2 packed two steps per reg

  // ---------------- forward ----------------
  float v0, v1, v2s;       // unnormalized predictive message
  auto fcore = [&](const Row& e, float& u0, float& u1, float& u2) -> float {
    u0 = v0 * e.x; u1 = v1 * e.y; u2 = v2s * e.z;   // e.z==0 on invalid lanes
    float S = wave_sum_b(u0 + u1 + u2);
    float os = off * S;
    v0 = __fmaf_rn(dd, u0, os);
    v1 = __fmaf_rn(dd, u1, os);
    v2s = __fmaf_rn(dd, u2, os);
    return S;
  };

  Row r0, r1, r2, r3;
  if (t0 == 0) {
    v0 = initd[c0]; v1 = initd[c1]; v2s = cok ? initd[c2] : 0.f;   // exact init
    r0 = ldraw(0); r1 = ldraw(1); r2 = ldraw(2); r3 = ldraw(3);
  } else {
    v0 = 1.f; v1 = 1.f; v2s = cok ? 1.f : 0.f;                     // warm from uniform
    const int ts = t0 - WARM;
    r0 = ldraw(ts); r1 = ldraw(ts + 1); r2 = ldraw(ts + 2); r3 = ldraw(ts + 3);
#pragma unroll
    for (int g = 0; g < WARM / 4; ++g) {
      const int tn = ts + 4 * g + 4;           // last group prefetches rows t0..t0+3
      Row n0 = ldraw(tn), n1 = ldraw(tn + 1), n2 = ldraw(tn + 2), n3 = ldraw(tn + 3);
      Row e0 = eRow(r0), e1 = eRow(r1), e2 = eRow(r2), e3 = eRow(r3);
      float u0, u1, u2;
      fcore(e0, u0, u1, u2);
      fcore(e1, u0, u1, u2);
      fcore(e2, u0, u1, u2);
      float S3 = fcore(e3, u0, u1, u2);
      float rs = __builtin_amdgcn_rcpf(S3);    // periodic rescale (pure scale)
      v0 *= rs; v1 *= rs; v2s *= rs;
      r0 = n0; r1 = n1; r2 = n2; r3 = n3;
    }
  }

  // main: fully unrolled, stores p-hat into registers at constant indices
#pragma unroll
  for (int i = 0; i < LCH; i += 4) {
    const int tn = t0 + i + 4;
    Row n0 = ldraw(tn + 0 > TT - 1 ? TT - 1 : tn + 0);
    Row n1 = ldraw(tn + 1 > TT - 1 ? TT - 1 : tn + 1);
    Row n2 = ldraw(tn + 2 > TT - 1 ? TT - 1 : tn + 2);
    Row n3 = ldraw(tn + 3 > TT - 1 ? TT - 1 : tn + 3);
    Row e0 = eRow(r0), e1 = eRow(r1), e2 = eRow(r2), e3 = eRow(r3);
    float u0, u1, u2;
    float S0 = fcore(e0, u0, u1, u2);
    float i0 = __builtin_amdgcn_rcpf(S0);
    ph01[i] = __floats2half2_rn(u0 * i0, u1 * i0);
    __half p2a = __float2half(u2 * i0);
    float S1 = fcore(e1, u0, u1, u2);
    float i1 = __builtin_amdgcn_rcpf(S1);
    ph01[i + 1] = __floats2half2_rn(u0 * i1, u1 * i1);
    ph2[i >> 1] = __halves2half2(p2a, __float2half(u2 * i1));
    float S2 = fcore(e2, u0, u1, u2);
    float i2 = __builtin_amdgcn_rcpf(S2);
    ph01[i + 2] = __floats2half2_rn(u0 * i2, u1 * i2);
    __half p2b = __float2half(u2 * i2);
    float S3 = fcore(e3, u0, u1, u2);
    float i3 = __builtin_amdgcn_rcpf(S3);
    ph01[i + 3] = __floats2half2_rn(u0 * i3, u1 * i3);
    ph2[(i >> 1) + 1] = __halves2half2(p2b, __float2half(u2 * i3));
    float rs = __builtin_amdgcn_rcpf(S3);
    v0 *= rs; v1 *= rs; v2s *= rs;
    r0 = n0; r1 = n1; r2 = n2; r3 = n3;
  }

  // ---------------- backward + fused posterior ----------------
  float q0 = 1.f, q1 = 1.f, q2 = cok ? 1.f : 0.f;   // exact for last chunk (beta_T=0)
  int te2 = t1 + WARM;
  if (te2 > TT) te2 = TT;

  auto ldB = [&](int tp1) -> Row {
    // step at time t uses logits[t+1]; t+1==TT => virtual row logit=0 (l=1)
    int rr = tp1 < 0 ? 0 : (tp1 > TT - 1 ? TT - 1 : tp1);
    Row w = ldraw(rr);
    if (tp1 >= TT) { w.x = 0.f; w.y = 0.f; w.z = 0.f; }
    return w;
  };
  auto bcore = [&](const Row& e) -> float {
    float w0 = e.x * q0, w1 = e.y * q1, w2 = e.z * q2;
    float S = wave_sum_b(w0 + w1 + w2);
    float os = off * S;
    q0 = __fmaf_rn(dd, w0, os);
    q1 = __fmaf_rn(dd, w1, os);
    q2 = __fmaf_rn(dd, w2, os);
    return S;
  };
  auto wpost = [&](int tt, int ta) {            // posterior_t = normalize(p-hat .* q)
    float a0 = __low2float(ph01[tt]) * q0;
    float a1 = __high2float(ph01[tt]) * q1;
    __half2 h2 = ph2[tt >> 1];
    float p2 = (tt & 1) ? __high2float(h2) : __low2float(h2);
    float a2 = cok ? p2 * q2 : 0.f;
    float z = wave_sum_b(a0 + a1 + a2);
    float iz = __builtin_amdgcn_rcpf(z);
    float* op = out + ((size_t)b * TT + ta) * NCLS;
    op[c0] = a0 * iz;
    op[c1] = a1 * iz;
    if (cok) op[c2] = a2 * iz;
  };

  // preload rows for steps te2-1..te2-4 (row = t+1)
  r0 = ldB(te2); r1 = ldB(te2 - 1); r2 = ldB(te2 - 2); r3 = ldB(te2 - 3);

  // warm-down: steps te2-1 .. t1 (16 steps interior, 0 for last chunk)
  for (int t = te2 - 1; t > t1 - 1; t -= 4) {
    Row n0 = ldB(t - 3), n1 = ldB(t - 4), n2 = ldB(t - 5), n3 = ldB(t - 6);
    Row e0 = eRow(r0), e1 = eRow(r1), e2 = eRow(r2), e3 = eRow(r3);
    bcore(e0); bcore(e1); bcore(e2);
    float S3 = bcore(e3);
    float rs = __builtin_amdgcn_rcpf(S3);
    q0 *= rs; q1 *= rs; q2 *= rs;
    r0 = n0; r1 = n1; r2 = n2; r3 = n3;
  }

  // main: fully unrolled, reads p-hat registers at constant indices
#pragma unroll
  for (int i = 0; i < LCH; i += 4) {
    const int t = t1 - 1 - i;                  // steps t..t-3; tt = LCH-1-i..LCH-4-i
    const int tt = LCH - 1 - i;
    Row n0 = ldB(t - 3), n1 = ldB(t - 4), n2 = ldB(t - 5), n3 = ldB(t - 6);
    Row e0 = eRow(r0), e1 = eRow(r1), e2 = eRow(r2), e3 = eRow(r3);
    bcore(e0); wpost(tt, t);
    bcore(e1); wpost(tt - 1, t - 1);
    bcore(e2); wpost(tt - 2, t - 2);
    float S3 = bcore(e3); wpost(tt - 3, t - 3);
    float rs = __builtin_amdgcn_rcpf(S3);
    q0 *= rs; q1 *= rs; q2 *= rs;
    r0 = n0; r1 = n1; r2 = n2; r3 = n3;
  }
}

extern "C" void kernel_launch(void* const* d_in, const int* in_sizes, int n_in,
                              void* d_out, int out_size, void* d_ws, size_t ws_size,
                              hipStream_t stream) {
  const float* logits = (const float*)d_in[0];
  const float* trans  = (const float*)d_in[1];
  const float* initd  = (const float*)d_in[2];
  float* out = (float*)d_out;
  dim3 grid(BB * NCHUNK);
  dim3 block(64);
  hipLaunchKernelGGL(hmm_fb, grid, block, 0, stream, logits, trans, initd, out);
}

// Round 3
// 59.648 us; speedup vs baseline: 5.0975x; 1.0829x over previous
//
#include <hip/hip_runtime.h>
#include <hip/hip_fp16.h>

// HMM forward-backward smoother, B=16, T=8192, C=170.
// T = off*11^T + (alpha-off)*I  =>  (u @ T)[j] = off*sum(u) + (alpha-off)*u[j]
// UNNORMALIZED scaled linear recursions (scale cancels in final softmax):
//   fwd:  v' = off*S + dd*u,  S = sum(u),  u = v*l_t   (rescale by 1/S every 4 steps)
//   bwd:  q' = off*S + dd*w,  S = sum(w),  w = l_{t+1}*q
// Wave-wide sum via DPP (v_add_f32_dpp row_shr/row_bcast + readlane 63).
// Chunked over time LCH=32, WARM=16 (mixing ~0.58/step => warm err ~1.7e-4 << 1.25e-2).
// p-hat split storage (spill-proof, learned from round-2 scratch spill):
//   p0,p1 packed __half2 in LDS (8192 B -> 20 WG/CU cap, one dispatch round)
//   p2 (42-lane tail) in 16 VGPRs, macro-unrolled LITERAL indices (rule #20)
// 4096 single-wave WGs = 16 WG/CU resident in one round at <=128 VGPR.

#define NCLS 170
#define BB 16
#define TT 8192
#define LCH 32
#define WARM 16
#define NCHUNK (TT / LCH)   // 256

struct Row { float x, y, z; };

// 64-lane sum, result broadcast to all lanes via readlane.
__device__ __forceinline__ float wave_sum_b(float x) {
  x += __int_as_float(__builtin_amdgcn_update_dpp(0, __float_as_int(x), 0x111, 0xF, 0xF, true)); // row_shr:1
  x += __int_as_float(__builtin_amdgcn_update_dpp(0, __float_as_int(x), 0x112, 0xF, 0xF, true)); // row_shr:2
  x += __int_as_float(__builtin_amdgcn_update_dpp(0, __float_as_int(x), 0x114, 0xF, 0xF, true)); // row_shr:4
  x += __int_as_float(__builtin_amdgcn_update_dpp(0, __float_as_int(x), 0x118, 0xF, 0xF, true)); // row_shr:8
  x += __int_as_float(__builtin_amdgcn_update_dpp(0, __float_as_int(x), 0x142, 0xA, 0xF, true)); // row_bcast:15
  x += __int_as_float(__builtin_amdgcn_update_dpp(0, __float_as_int(x), 0x143, 0xC, 0xF, true)); // row_bcast:31
  return __int_as_float(__builtin_amdgcn_readlane(__float_as_int(x), 63));
}

__global__ __launch_bounds__(64, 4) void hmm_fb(const float* __restrict__ logits,
                                                const float* __restrict__ trans,
                                                const float* __restrict__ initd,
                                                float* __restrict__ out) {
  __shared__ __half2 pb01[LCH * 64];   // 8192 B: (p0,p1) per step per lane, stride-1 dwords
  const int lane = threadIdx.x;

  // XCD-aware swizzle: 4096 WGs, 8 XCDs -> contiguous ranges per XCD.
  const int d = blockIdx.x;
  const int o = (d & 7) * (BB * NCHUNK / 8) + (d >> 3);
  const int b = o / NCHUNK;
  const int chunk = o % NCHUNK;
  const int t0 = chunk * LCH;
  const int t1 = t0 + LCH;

  // reference uses log(T + 1e-12); reproduce exactly in linear domain
  const float off = trans[1] + 1e-12f;   // off-diagonal element
  const float dia = trans[0] + 1e-12f;   // diagonal element
  const float dd = dia - off;

  const int c0 = lane, c1 = lane + 64, c2 = lane + 128;
  const bool cok = (c2 < NCLS);
  const float* lg = logits + (size_t)b * TT * NCLS;

  auto ldraw = [&](int t) -> Row {
    const float* r = lg + (size_t)t * NCLS;
    Row w;
    w.x = r[c0];
    w.y = r[c1];
    w.z = cok ? r[c2] : 0.f;
    return w;
  };
  auto eRow = [&](const Row& w) -> Row {
    Row e;
    e.x = __expf(w.x);
    e.y = __expf(w.y);
    e.z = cok ? __expf(w.z) : 0.f;
    return e;
  };

  __half2 ph2[LCH / 2];   // p2 two steps per reg; LITERAL indices only (macro-unrolled)

  // ---------------- forward ----------------
  float v0, v1, v2s;      // unnormalized predictive message
  auto fcore = [&](const Row& e, float& u0, float& u1, float& u2) -> float {
    u0 = v0 * e.x; u1 = v1 * e.y; u2 = v2s * e.z;   // e.z==0 on invalid lanes
    float S = wave_sum_b(u0 + u1 + u2);
    float os = off * S;
    v0 = __fmaf_rn(dd, u0, os);
    v1 = __fmaf_rn(dd, u1, os);
    v2s = __fmaf_rn(dd, u2, os);
    return S;
  };

  Row r0, r1, r2, r3;
  if (t0 == 0) {
    v0 = initd[c0]; v1 = initd[c1]; v2s = cok ? initd[c2] : 0.f;   // exact init
    r0 = ldraw(0); r1 = ldraw(1); r2 = ldraw(2); r3 = ldraw(3);
  } else {
    v0 = 1.f; v1 = 1.f; v2s = cok ? 1.f : 0.f;                     // warm from uniform
    const int ts = t0 - WARM;
    r0 = ldraw(ts); r1 = ldraw(ts + 1); r2 = ldraw(ts + 2); r3 = ldraw(ts + 3);
#pragma unroll
    for (int g = 0; g < WARM / 4; ++g) {
      const int tn = ts + 4 * g + 4;           // last group prefetches rows t0..t0+3
      Row n0 = ldraw(tn), n1 = ldraw(tn + 1), n2 = ldraw(tn + 2), n3 = ldraw(tn + 3);
      Row e0 = eRow(r0), e1 = eRow(r1), e2 = eRow(r2), e3 = eRow(r3);
      float u0, u1, u2;
      fcore(e0, u0, u1, u2);
      fcore(e1, u0, u1, u2);
      fcore(e2, u0, u1, u2);
      float S3 = fcore(e3, u0, u1, u2);
      float rs = __builtin_amdgcn_rcpf(S3);    // periodic rescale (pure scale)
      v0 *= rs; v1 *= rs; v2s *= rs;
      r0 = n0; r1 = n1; r2 = n2; r3 = n3;
    }
  }

// fwd main: macro-unrolled groups of 4; (i) is a literal constant
#define FGROUP(i)                                                              \
  {                                                                            \
    const int tn = t0 + (i) + 4;                                               \
    Row n0 = ldraw(tn + 0 > TT - 1 ? TT - 1 : tn + 0);                         \
    Row n1 = ldraw(tn + 1 > TT - 1 ? TT - 1 : tn + 1);                         \
    Row n2 = ldraw(tn + 2 > TT - 1 ? TT - 1 : tn + 2);                         \
    Row n3 = ldraw(tn + 3 > TT - 1 ? TT - 1 : tn + 3);                         \
    Row e0 = eRow(r0), e1 = eRow(r1), e2 = eRow(r2), e3 = eRow(r3);            \
    float u0, u1, u2;                                                          \
    float S0 = fcore(e0, u0, u1, u2);                                          \
    float x0 = __builtin_amdgcn_rcpf(S0);                                      \
    pb01[((i) + 0) * 64 + lane] = __floats2half2_rn(u0 * x0, u1 * x0);         \
    __half pa = __float2half(u2 * x0);                                         \
    float S1 = fcore(e1, u0, u1, u2);                                          \
    float x1 = __builtin_amdgcn_rcpf(S1);                                      \
    pb01[((i) + 1) * 64 + lane] = __floats2half2_rn(u0 * x1, u1 * x1);         \
    ph2[(i) / 2] = __halves2half2(pa, __float2half(u2 * x1));                  \
    float S2 = fcore(e2, u0, u1, u2);                                          \
    float x2 = __builtin_amdgcn_rcpf(S2);                                      \
    pb01[((i) + 2) * 64 + lane] = __floats2half2_rn(u0 * x2, u1 * x2);         \
    __half pb = __float2half(u2 * x2);                                         \
    float S3 = fcore(e3, u0, u1, u2);                                          \
    float x3 = __builtin_amdgcn_rcpf(S3);                                      \
    pb01[((i) + 3) * 64 + lane] = __floats2half2_rn(u0 * x3, u1 * x3);         \
    ph2[(i) / 2 + 1] = __halves2half2(pb, __float2half(u2 * x3));              \
    v0 *= x3; v1 *= x3; v2s *= x3;  /* periodic rescale (pure scale) */        \
    r0 = n0; r1 = n1; r2 = n2; r3 = n3;                                        \
  }

  FGROUP(0) FGROUP(4) FGROUP(8) FGROUP(12)
  FGROUP(16) FGROUP(20) FGROUP(24) FGROUP(28)
#undef FGROUP

  // ---------------- backward + fused posterior ----------------
  float q0 = 1.f, q1 = 1.f, q2 = cok ? 1.f : 0.f;   // exact for last chunk (beta_T=0)
  int te2 = t1 + WARM;
  if (te2 > TT) te2 = TT;

  auto ldB = [&](int tp1) -> Row {
    // step at time t uses logits[t+1]; t+1==TT => virtual row logit=0 (l=1)
    int rr = tp1 < 0 ? 0 : (tp1 > TT - 1 ? TT - 1 : tp1);
    Row w = ldraw(rr);
    if (tp1 >= TT) { w.x = 0.f; w.y = 0.f; w.z = 0.f; }
    return w;
  };
  auto bcore = [&](const Row& e) -> float {
    float w0 = e.x * q0, w1 = e.y * q1, w2 = e.z * q2;
    float S = wave_sum_b(w0 + w1 + w2);
    float os = off * S;
    q0 = __fmaf_rn(dd, w0, os);
    q1 = __fmaf_rn(dd, w1, os);
    q2 = __fmaf_rn(dd, w2, os);
    return S;
  };

  // preload rows for steps te2-1..te2-4 (row = t+1)
  r0 = ldB(te2); r1 = ldB(te2 - 1); r2 = ldB(te2 - 2); r3 = ldB(te2 - 3);

  // warm-down: steps te2-1 .. t1 (16 steps interior, 0 for last chunk); no ph access
  for (int t = te2 - 1; t > t1 - 1; t -= 4) {
    Row n0 = ldB(t - 3), n1 = ldB(t - 4), n2 = ldB(t - 5), n3 = ldB(t - 6);
    Row e0 = eRow(r0), e1 = eRow(r1), e2 = eRow(r2), e3 = eRow(r3);
    bcore(e0); bcore(e1); bcore(e2);
    float S3 = bcore(e3);
    float rs = __builtin_amdgcn_rcpf(S3);
    q0 *= rs; q1 *= rs; q2 *= rs;
    r0 = n0; r1 = n1; r2 = n2; r3 = n3;
  }

// posterior_t = normalize(p-hat .* q); (tt) is a literal constant
#define WPOST(tt, ta)                                                          \
  {                                                                            \
    __half2 h01 = pb01[(tt) * 64 + lane];                                      \
    float a0 = __low2float(h01) * q0;                                          \
    float a1 = __high2float(h01) * q1;                                         \
    __half2 h2v = ph2[(tt) >> 1];                                              \
    float p2f = ((tt) & 1) ? __high2float(h2v) : __low2float(h2v);             \
    float a2 = cok ? p2f * q2 : 0.f;                                           \
    float z = wave_sum_b(a0 + a1 + a2);                                        \
    float iz = __builtin_amdgcn_rcpf(z);                                       \
    float* op = out + ((size_t)b * TT + (ta)) * NCLS;                          \
    op[c0] = a0 * iz;                                                          \
    op[c1] = a1 * iz;                                                          \
    if (cok) op[c2] = a2 * iz;                                                 \
  }

// bwd main: macro-unrolled groups of 4; (i) literal; steps t1-1-(i) .. t1-4-(i)
#define BGROUP(i)                                                              \
  {                                                                            \
    const int t = t1 - 1 - (i);                                                \
    Row n0 = ldB(t - 3), n1 = ldB(t - 4), n2 = ldB(t - 5), n3 = ldB(t - 6);    \
    Row e0 = eRow(r0), e1 = eRow(r1), e2 = eRow(r2), e3 = eRow(r3);            \
    bcore(e0); WPOST(LCH - 1 - (i), t)                                         \
    bcore(e1); WPOST(LCH - 2 - (i), t - 1)                                     \
    bcore(e2); WPOST(LCH - 3 - (i), t - 2)                                     \
    float S3 = bcore(e3); WPOST(LCH - 4 - (i), t - 3)                          \
    float rs = __builtin_amdgcn_rcpf(S3);                                      \
    q0 *= rs; q1 *= rs; q2 *= rs;                                              \
    r0 = n0; r1 = n1; r2 = n2; r3 = n3;                                        \
  }

  BGROUP(0) BGROUP(4) BGROUP(8) BGROUP(12)
  BGROUP(16) BGROUP(20) BGROUP(24) BGROUP(28)
#undef BGROUP
#undef WPOST
}

extern "C" void kernel_launch(void* const* d_in, const int* in_sizes, int n_in,
                              void* d_out, int out_size, void* d_ws, size_t ws_size,
                              hipStream_t stream) {
  const float* logits = (const float*)d_in[0];
  const float* trans  = (const float*)d_in[1];
  const float* initd  = (const float*)d_in[2];
  float* out = (float*)d_out;
  dim3 grid(BB * NCHUNK);
  dim3 block(64);
  hipLaunchKernelGGL(hmm_fb, grid, block, 0, stream, logits, trans, initd, out);
}

// Round 4
// 59.023 us; speedup vs baseline: 5.1515x; 1.0106x over previous
//
#include <hip/hip_runtime.h>
#include <hip/hip_fp16.h>

// HMM forward-backward smoother, B=16, T=8192, C=170.
// T = off*11^T + (alpha-off)*I  =>  (u @ T)[j] = off*sum(u) + (alpha-off)*u[j]
// UNNORMALIZED scaled linear recursions (scale cancels in final softmax):
//   fwd:  v' = off*S + dd*u,  S = sum(u),  u = v*l_t   (rescale by 1/S every 4 steps)
//   bwd:  q' = off*S + dd*w,  S = sum(w),  w = l_{t+1}*q
// Wave-wide sum via DPP (v_add_f32_dpp row_shr/row_bcast + readlane 63).
// Chunked over time LCH=32, WARM=16 (mixing ~0.58/step => warm err ~1.7e-4 << 1.25e-2).
// Round-4 changes:
//  * 8-deep row prefetch (two 4-row banks, ping-pong through warm->main handoff):
//    ~400+ chain-cycles of load cover vs ~200 before; attacks the exposed
//    HBM/L2 latency that held VALUBusy at 33%.
//  * float2 class map: lane l owns classes {2l, 2l+1, 128+l} -> 2 VMEM ops/row
//    instead of 3 (legal: wave_sum covers all classes; scalars mapping-free).
// p-hat split storage: (p_{2l},p_{2l+1}) __half2 in LDS (8 KB), tail class in
// 16 VGPRs with macro-unrolled LITERAL indices (spill-proof, rule #20).
// 4096 single-wave WGs = 16 WG/CU in one dispatch round at <=128 VGPR.

#define NCLS 170
#define BB 16
#define TT 8192
#define LCH 32
#define WARM 16
#define NCHUNK (TT / LCH)   // 256

struct Row { float x, y, z; };

// 64-lane sum, result broadcast to all lanes via readlane.
__device__ __forceinline__ float wave_sum_b(float x) {
  x += __int_as_float(__builtin_amdgcn_update_dpp(0, __float_as_int(x), 0x111, 0xF, 0xF, true)); // row_shr:1
  x += __int_as_float(__builtin_amdgcn_update_dpp(0, __float_as_int(x), 0x112, 0xF, 0xF, true)); // row_shr:2
  x += __int_as_float(__builtin_amdgcn_update_dpp(0, __float_as_int(x), 0x114, 0xF, 0xF, true)); // row_shr:4
  x += __int_as_float(__builtin_amdgcn_update_dpp(0, __float_as_int(x), 0x118, 0xF, 0xF, true)); // row_shr:8
  x += __int_as_float(__builtin_amdgcn_update_dpp(0, __float_as_int(x), 0x142, 0xA, 0xF, true)); // row_bcast:15
  x += __int_as_float(__builtin_amdgcn_update_dpp(0, __float_as_int(x), 0x143, 0xC, 0xF, true)); // row_bcast:31
  return __int_as_float(__builtin_amdgcn_readlane(__float_as_int(x), 63));
}

__global__ __launch_bounds__(64, 4) void hmm_fb(const float* __restrict__ logits,
                                                const float* __restrict__ trans,
                                                const float* __restrict__ initd,
                                                float* __restrict__ out) {
  __shared__ __half2 pb01[LCH * 64];   // 8192 B: (p_{2l},p_{2l+1}) per step per lane
  const int lane = threadIdx.x;

  // XCD-aware swizzle: 4096 WGs, 8 XCDs -> contiguous ranges per XCD.
  const int d = blockIdx.x;
  const int o = (d & 7) * (BB * NCHUNK / 8) + (d >> 3);
  const int b = o / NCHUNK;
  const int chunk = o % NCHUNK;
  const int t0 = chunk * LCH;
  const int t1 = t0 + LCH;

  // reference uses log(T + 1e-12); reproduce exactly in linear domain
  const float off = trans[1] + 1e-12f;   // off-diagonal element
  const float dia = trans[0] + 1e-12f;   // diagonal element
  const float dd = dia - off;

  const bool cok = (lane < NCLS - 128);  // 42 tail lanes
  const float* lg = logits + (size_t)b * TT * NCLS;

  auto ldraw = [&](int t) -> Row {
    const float* r = lg + (size_t)t * NCLS;
    float2 xy = *(const float2*)(r + 2 * lane);   // classes 2l, 2l+1 (8B coalesced)
    Row w;
    w.x = xy.x;
    w.y = xy.y;
    w.z = cok ? r[128 + lane] : 0.f;              // tail class 128+l
    return w;
  };
  auto eRow = [&](const Row& w) -> Row {
    Row e;
    e.x = __expf(w.x);
    e.y = __expf(w.y);
    e.z = cok ? __expf(w.z) : 0.f;
    return e;
  };

  __half2 ph2[LCH / 2];   // tail-class p, two steps per reg; LITERAL indices only

  // ---------------- forward ----------------
  float v0, v1, v2s;      // unnormalized predictive message
  auto fcore = [&](const Row& e, float& u0, float& u1, float& u2) -> float {
    u0 = v0 * e.x; u1 = v1 * e.y; u2 = v2s * e.z;   // e.z==0 on invalid lanes
    float S = wave_sum_b(u0 + u1 + u2);
    float os = off * S;
    v0 = __fmaf_rn(dd, u0, os);
    v1 = __fmaf_rn(dd, u1, os);
    v2s = __fmaf_rn(dd, u2, os);
    return S;
  };

  Row a0, a1, a2, a3, b0, b1, b2, b3;
  int ts;
  if (t0 == 0) {
    ts = 0;                                   // exact initial distribution
    float2 i01 = *(const float2*)(initd + 2 * lane);
    v0 = i01.x; v1 = i01.y; v2s = cok ? initd[128 + lane] : 0.f;
  } else {
    ts = t0 - WARM;                           // warm from uniform
    v0 = 1.f; v1 = 1.f; v2s = cok ? 1.f : 0.f;
  }
  a0 = ldraw(ts); a1 = ldraw(ts + 1); a2 = ldraw(ts + 2); a3 = ldraw(ts + 3);
  b0 = ldraw(ts + 4); b1 = ldraw(ts + 5); b2 = ldraw(ts + 6); b3 = ldraw(ts + 7);

  // warm loop: (t0-ts)/4 = 4 groups interior, 0 for chunk 0; no ph writes
  for (int g = 0; g < (t0 - ts) / 4; ++g) {
    const int tn = ts + 8 + 4 * g;            // prefetch 2 groups ahead
    Row n0 = ldraw(tn), n1 = ldraw(tn + 1), n2 = ldraw(tn + 2), n3 = ldraw(tn + 3);
    Row e0 = eRow(a0), e1 = eRow(a1), e2 = eRow(a2), e3 = eRow(a3);
    float u0, u1, u2;
    fcore(e0, u0, u1, u2);
    fcore(e1, u0, u1, u2);
    fcore(e2, u0, u1, u2);
    float S3 = fcore(e3, u0, u1, u2);
    float rs = __builtin_amdgcn_rcpf(S3);     // periodic rescale (pure scale)
    v0 *= rs; v1 *= rs; v2s *= rs;
    a0 = b0; a1 = b1; a2 = b2; a3 = b3;
    b0 = n0; b1 = n1; b2 = n2; b3 = n3;
  }
  // handoff: a = rows t0..t0+3, b = rows t0+4..t0+7

// fwd main: macro-unrolled groups of 4; (i) is a literal constant
#define FGROUP(i)                                                              \
  {                                                                            \
    const int tn = t0 + (i) + 8;                                               \
    Row n0 = ldraw(tn + 0 > t1 - 1 ? t1 - 1 : tn + 0);                         \
    Row n1 = ldraw(tn + 1 > t1 - 1 ? t1 - 1 : tn + 1);                         \
    Row n2 = ldraw(tn + 2 > t1 - 1 ? t1 - 1 : tn + 2);                         \
    Row n3 = ldraw(tn + 3 > t1 - 1 ? t1 - 1 : tn + 3);                         \
    Row e0 = eRow(a0), e1 = eRow(a1), e2 = eRow(a2), e3 = eRow(a3);            \
    float u0, u1, u2;                                                          \
    float S0 = fcore(e0, u0, u1, u2);                                          \
    float x0 = __builtin_amdgcn_rcpf(S0);                                      \
    pb01[((i) + 0) * 64 + lane] = __floats2half2_rn(u0 * x0, u1 * x0);         \
    __half pa = __float2half(u2 * x0);                                         \
    float S1 = fcore(e1, u0, u1, u2);                                          \
    float x1 = __builtin_amdgcn_rcpf(S1);                                      \
    pb01[((i) + 1) * 64 + lane] = __floats2half2_rn(u0 * x1, u1 * x1);         \
    ph2[(i) / 2] = __halves2half2(pa, __float2half(u2 * x1));                  \
    float S2 = fcore(e2, u0, u1, u2);                                          \
    float x2 = __builtin_amdgcn_rcpf(S2);                                      \
    pb01[((i) + 2) * 64 + lane] = __floats2half2_rn(u0 * x2, u1 * x2);         \
    __half pb = __float2half(u2 * x2);                                         \
    float S3 = fcore(e3, u0, u1, u2);                                          \
    float x3 = __builtin_amdgcn_rcpf(S3);                                      \
    pb01[((i) + 3) * 64 + lane] = __floats2half2_rn(u0 * x3, u1 * x3);         \
    ph2[(i) / 2 + 1] = __halves2half2(pb, __float2half(u2 * x3));              \
    v0 *= x3; v1 *= x3; v2s *= x3;  /* periodic rescale (pure scale) */        \
    a0 = b0; a1 = b1; a2 = b2; a3 = b3;                                        \
    b0 = n0; b1 = n1; b2 = n2; b3 = n3;                                        \
  }

  FGROUP(0) FGROUP(4) FGROUP(8) FGROUP(12)
  FGROUP(16) FGROUP(20) FGROUP(24) FGROUP(28)
#undef FGROUP

  // ---------------- backward + fused posterior ----------------
  float q0 = 1.f, q1 = 1.f, q2 = cok ? 1.f : 0.f;   // exact for last chunk (beta_T=0)
  int te2 = t1 + WARM;
  if (te2 > TT) te2 = TT;
  const int tstart = te2 - 1;

  auto ldB = [&](int tp1) -> Row {
    // step at time t uses logits[t+1]; t+1==TT => virtual row logit=0 (l=1)
    int rr = tp1 < 0 ? 0 : (tp1 > TT - 1 ? TT - 1 : tp1);
    Row w = ldraw(rr);
    if (tp1 >= TT) { w.x = 0.f; w.y = 0.f; w.z = 0.f; }
    return w;
  };
  auto bcore = [&](const Row& e) -> float {
    float w0 = e.x * q0, w1 = e.y * q1, w2 = e.z * q2;
    float S = wave_sum_b(w0 + w1 + w2);
    float os = off * S;
    q0 = __fmaf_rn(dd, w0, os);
    q1 = __fmaf_rn(dd, w1, os);
    q2 = __fmaf_rn(dd, w2, os);
    return S;
  };

  // banks: a = rows for steps tstart..tstart-3, b = next 4 steps
  a0 = ldB(tstart + 1); a1 = ldB(tstart); a2 = ldB(tstart - 1); a3 = ldB(tstart - 2);
  b0 = ldB(tstart - 3); b1 = ldB(tstart - 4); b2 = ldB(tstart - 5); b3 = ldB(tstart - 6);

  // warm-down: (te2-t1)/4 = 4 groups interior, 0 for last chunk; no ph access
  for (int g = 0; g < (te2 - t1) / 4; ++g) {
    const int tp = tstart - 7 - 4 * g;        // prefetch rows for 2 groups ahead
    Row n0 = ldB(tp), n1 = ldB(tp - 1), n2 = ldB(tp - 2), n3 = ldB(tp - 3);
    Row e0 = eRow(a0), e1 = eRow(a1), e2 = eRow(a2), e3 = eRow(a3);
    bcore(e0); bcore(e1); bcore(e2);
    float S3 = bcore(e3);
    float rs = __builtin_amdgcn_rcpf(S3);
    q0 *= rs; q1 *= rs; q2 *= rs;
    a0 = b0; a1 = b1; a2 = b2; a3 = b3;
    b0 = n0; b1 = n1; b2 = n2; b3 = n3;
  }
  // handoff: a = rows for steps t1-1..t1-4 (rows t1..t1-3), b = rows t1-4..t1-7

// posterior_t = normalize(p-hat .* q); (tt) is a literal constant
#define WPOST(tt, ta)                                                          \
  {                                                                            \
    __half2 h01 = pb01[(tt) * 64 + lane];                                      \
    float g0 = __low2float(h01) * q0;                                          \
    float g1 = __high2float(h01) * q1;                                         \
    __half2 h2v = ph2[(tt) >> 1];                                              \
    float p2f = ((tt) & 1) ? __high2float(h2v) : __low2float(h2v);             \
    float g2 = cok ? p2f * q2 : 0.f;                                           \
    float z = wave_sum_b(g0 + g1 + g2);                                        \
    float iz = __builtin_amdgcn_rcpf(z);                                       \
    float* op = out + ((size_t)b * TT + (ta)) * NCLS;                          \
    float2 o01; o01.x = g0 * iz; o01.y = g1 * iz;                              \
    *(float2*)(op + 2 * lane) = o01;                                           \
    if (cok) op[128 + lane] = g2 * iz;                                         \
  }

// bwd main: macro-unrolled groups of 4; (i) literal; steps t1-1-(i) .. t1-4-(i)
#define BGROUP(i)                                                              \
  {                                                                            \
    const int tp = t1 - 8 - (i);              /* rows for 2 groups ahead */    \
    Row n0 = ldB(tp + 0 < t0 + 1 ? t0 + 1 : tp + 0);                           \
    Row n1 = ldB(tp - 1 < t0 + 1 ? t0 + 1 : tp - 1);                           \
    Row n2 = ldB(tp - 2 < t0 + 1 ? t0 + 1 : tp - 2);                           \
    Row n3 = ldB(tp - 3 < t0 + 1 ? t0 + 1 : tp - 3);                           \
    Row e0 = eRow(a0), e1 = eRow(a1), e2 = eRow(a2), e3 = eRow(a3);            \
    const int t = t1 - 1 - (i);                                                \
    bcore(e0); WPOST(LCH - 1 - (i), t)                                         \
    bcore(e1); WPOST(LCH - 2 - (i), t - 1)                                     \
    bcore(e2); WPOST(LCH - 3 - (i), t - 2)                                     \
    float S3 = bcore(e3); WPOST(LCH - 4 - (i), t - 3)                          \
    float rs = __builtin_amdgcn_rcpf(S3);                                      \
    q0 *= rs; q1 *= rs; q2 *= rs;                                              \
    a0 = b0; a1 = b1; a2 = b2; a3 = b3;                                        \
    b0 = n0; b1 = n1; b2 = n2; b3 = n3;                                        \
  }

  BGROUP(0) BGROUP(4) BGROUP(8) BGROUP(12)
  BGROUP(16) BGROUP(20) BGROUP(24) BGROUP(28)
#undef BGROUP
#undef WPOST
}

extern "C" void kernel_launch(void* const* d_in, const int* in_sizes, int n_in,
                              void* d_out, int out_size, void* d_ws, size_t ws_size,
                              hipStream_t stream) {
  const float* logits = (const float*)d_in[0];
  const float* trans  = (const float*)d_in[1];
  const float* initd  = (const float*)d_in[2];
  float* out = (float*)d_out;
  dim3 grid(BB * NCHUNK);
  dim3 block(64);
  hipLaunchKernelGGL(hmm_fb, grid, block, 0, stream, logits, trans, initd, out);
}